// Round 12
// baseline (218.466 us; speedup 1.0000x reference)
//
#include <hip/hip_runtime.h>
#include <math.h>

#define DIM     512
#define NNODES  10000
#define NEDGES  200000
#define MPAD    10240   // 160 * 64 (padded so XCD packing is exact)
#define NMB     160     // m-groups of 64
#define GEMM_GRID (NMB * 4)       // 640
#define BKT     157               // r>>6 buckets (matches GEMM m-groups)

// D2 roles: [0,640) gemm+score | [640,704) hist | [704] scan | [705,904) scatter.
// GEMM first (bid&7 keeps the XCD bijection); sort roles at high bids are
// deadlock-free under ascending OR descending dispatch order (hist+scan fit
// in the residual resident slots; scatter blocks cycle through freed slots).
#define GEMM_N     640
#define HIST_BASE  640
#define HIST_BLK   64
#define SCAN_BID   704
#define SCAT_BASE  705
#define SCAT_N     199
#define FUSE_GRID  904

using floatx4 = __attribute__((ext_vector_type(4))) float;
using half8   = __attribute__((ext_vector_type(8))) _Float16;
using half2v  = __attribute__((ext_vector_type(2))) _Float16;
typedef unsigned long long ull;

template <int N> struct IC { static constexpr int v = N; };

__device__ inline float dot2acc(half2v a, half2v b, float c) {
#if __has_builtin(__builtin_amdgcn_fdot2)
    return __builtin_amdgcn_fdot2(a, b, c, false);
#else
    return fmaf((float)a[0], (float)b[0], fmaf((float)a[1], (float)b[1], c));
#endif
}

__device__ inline int aload(const int* p) {
    return __hip_atomic_load(p, __ATOMIC_RELAXED, __HIP_MEMORY_SCOPE_AGENT);
}
__device__ inline void astore(int* p, int v) {
    __hip_atomic_store(p, v, __ATOMIC_RELAXED, __HIP_MEMORY_SCOPE_AGENT);
}
// RELAXED poll (R3-proven): acquire polls invalidate the XCD L2 per iteration
// and poisoned the chip in R2. Flags/counts/cursor flow through agent-scope
// atomics (coherence point). slots are REGULAR stores -> need a proper
// ONE-SHOT release/acquire pair across XCDs (R11's NaN: regular stores sat
// dirty in the writer XCD's L2, readers on other XCDs saw stale garbage).
__device__ inline void waitflag(int* f, int target) {
    while (__hip_atomic_load(f, __ATOMIC_RELAXED, __HIP_MEMORY_SCOPE_AGENT) < target)
        __builtin_amdgcn_s_sleep(8);
    __atomic_signal_fence(__ATOMIC_ACQUIRE);
}
// poll relaxed, then ONE acquire load (single L1/L2 invalidate per block)
__device__ inline void waitflag_acq(int* f, int target) {
    while (__hip_atomic_load(f, __ATOMIC_RELAXED, __HIP_MEMORY_SCOPE_AGENT) < target)
        __builtin_amdgcn_s_sleep(8);
    (void)__hip_atomic_load(f, __ATOMIC_ACQUIRE, __HIP_MEMORY_SCOPE_AGENT);
}
__device__ inline void signal(int* f) {
    __atomic_signal_fence(__ATOMIC_RELEASE);
    __hip_atomic_fetch_add(f, 1, __ATOMIC_RELAXED, __HIP_MEMORY_SCOPE_AGENT);
}
// release RMW: writes back this XCD's L2 (dirty slot lines) then signals
__device__ inline void signal_rel(int* f) {
    __hip_atomic_fetch_add(f, 1, __ATOMIC_RELEASE, __HIP_MEMORY_SCOPE_AGENT);
}

// ---------------------------------------------------------------------------
// prep: (a) Z fp32 -> Zh16 fp16 (pad rows zeroed)  (b) W -> Wh16t transpose
//       (c) zero counts[157]+flags[4] (block 0) and score_acc[200k] (b<196).
// ---------------------------------------------------------------------------
#define PREP_ZBLK 2560            // MPAD*512/(256*8)
#define PREP_GRID (PREP_ZBLK + 64)
__global__ __launch_bounds__(256) void prep(const float* __restrict__ Z,
                                            const float* __restrict__ W,
                                            _Float16* __restrict__ Zh16,
                                            _Float16* __restrict__ Wh16t,
                                            int* __restrict__ counts,
                                            float* __restrict__ score_acc) {
    const int b = blockIdx.x;
    const int t = threadIdx.x;

    if (b == 0 && t < BKT + 4) counts[t] = 0;   // counts + adjacent flags
    if (b < 196) {                              // zero score_acc (50000 float4)
        int i = b * 256 + t;
        if (i < NEDGES / 4)
            ((float4*)score_acc)[i] = make_float4(0.f, 0.f, 0.f, 0.f);
    }

    if (b < PREP_ZBLK) {
        const int idx8 = (b * 256 + t) * 8;
        const int m = idx8 >> 9;
        float x[8];
        if (m < NNODES) {
            float4 v0 = *(const float4*)(Z + idx8);
            float4 v1 = *(const float4*)(Z + idx8 + 4);
            x[0]=v0.x; x[1]=v0.y; x[2]=v0.z; x[3]=v0.w;
            x[4]=v1.x; x[5]=v1.y; x[6]=v1.z; x[7]=v1.w;
        } else {
            #pragma unroll
            for (int j = 0; j < 8; ++j) x[j] = 0.f;
        }
        half8 h;
        #pragma unroll
        for (int j = 0; j < 8; ++j) h[j] = (_Float16)x[j];
        *(half8*)(Zh16 + idx8) = h;
    } else {
        __shared__ float tile[64][65];
        const int wb = b - PREP_ZBLK;      // 0..63
        const int kb = (wb >> 3) * 64;
        const int nb = (wb & 7) * 64;
        const int kk = t >> 2;
        const int ch = t & 3;

        const float* src = W + (size_t)(kb + kk) * DIM + nb + ch * 16;
        #pragma unroll
        for (int q = 0; q < 4; ++q) {
            float4 v = *(const float4*)(src + q * 4);
            tile[kk][ch * 16 + q * 4 + 0] = v.x;
            tile[kk][ch * 16 + q * 4 + 1] = v.y;
            tile[kk][ch * 16 + q * 4 + 2] = v.z;
            tile[kk][ch * 16 + q * 4 + 3] = v.w;
        }
        __syncthreads();

        const int nn = kk;
        half8 h0, h1;
        #pragma unroll
        for (int i = 0; i < 8; ++i) h0[i] = (_Float16)tile[ch * 16 + i][nn];
        #pragma unroll
        for (int i = 0; i < 8; ++i) h1[i] = (_Float16)tile[ch * 16 + 8 + i][nn];
        _Float16* d = Wh16t + (size_t)(nb + nn) * DIM + kb + ch * 16;
        *(half8*)(d)     = h0;
        *(half8*)(d + 8) = h1;
    }
}

// ---------------------------------------------------------------------------
// D2: GEMM with FUSED edge scoring (R11 structure, visibility-fixed).
// Edges bucketed by r>>6 (= GEMM m-group) via LDS-aggregated hist/scan/
// scatter roles, hidden under the MFMA phase. After its 8 K-steps each GEMM
// block spills its 64x128 fp32 tile to LDS (aliasing the dead staging
// buffers) and scores its bucket over its n-slice: ZW row from LDS (r-side
// gather + 10.5MB ZWh write DELETED), Zh16[c] 256B from global, fp32 partial
// atomicAdd into score_acc (4 partials/edge).
// Handoff: scatter signal_rel (L2 writeback) -> gemm waitflag_acq (one L2
// invalidate, after staging is consumed) -> regular cached slot reads.
// flags[0]: hist done (64); flags[1]: cursor ready (1); flags[2]: scatter (199).
// ---------------------------------------------------------------------------
#define ZWL_LD 132   // fp32 row stride (padded)
__global__ __launch_bounds__(256, 3) void gemm_sort(
        const _Float16* __restrict__ Zh16,
        const _Float16* __restrict__ Wh16t,
        const int* __restrict__ eidx,
        int* __restrict__ counts,
        int* __restrict__ cursor,
        ull* __restrict__ slots,
        float* __restrict__ score_acc,
        int* __restrict__ flags)
{
    __shared__ __align__(16) char smem[49152];          // Abuf|Bbuf, then ZWl
    _Float16 (*Abuf)[2 * 64 * 32]  = reinterpret_cast<_Float16(*)[2 * 64 * 32]>(smem);
    _Float16 (*Bbuf)[2 * 128 * 32] = reinterpret_cast<_Float16(*)[2 * 128 * 32]>(smem + 16384);
    float* ZWl = reinterpret_cast<float*>(smem);        // 64*132*4 = 33792 B
    __shared__ int s_cnt[BKT], s_base[BKT], s_off[BKT];
    __shared__ int s_scan[256];

    const int t   = threadIdx.x;
    const int bid = blockIdx.x;

    // ---------------- role: GEMM + fused scoring ----------------
    if (bid < GEMM_N) {
        const int cxd = bid & 7;              // XCD class
        const int rr  = bid >> 3;             // 0..79
        const int mg  = (rr >> 2) * 8 + cxd;  // 0..159, same-m => same XCD
        const int m0  = mg * 64;
        const int n0  = (rr & 3) * 128;

        const int l  = t & 63;
        const int w  = t >> 6;
        const int wn = w * 32;
        const int lm = l & 15;
        const int lq = l >> 4;
        const unsigned wbase = (unsigned)(t & 192);

        floatx4 acc[4][2] = {};

        auto stage = [&](int buf, int k0) {
            #pragma unroll
            for (int p = 0; p < 2; ++p) {
                const int s   = p * 256 + t;
                const int kk  = s >> 8;
                const int row = (s >> 2) & 63;
                const int ch  = s & 3;
                const _Float16* src = Zh16 + (size_t)(m0 + row) * DIM + k0 + kk * 32 + ch * 8;
                __builtin_amdgcn_global_load_lds(
                    (const __attribute__((address_space(1))) void*)src,
                    (__attribute__((address_space(3))) void*)&Abuf[buf][(p * 256 + wbase) * 8],
                    16, 0, 0);
            }
            #pragma unroll
            for (int p = 0; p < 4; ++p) {
                const int s   = p * 256 + t;
                const int kk  = s >> 9;
                const int row = (s >> 2) & 127;
                const int ch  = s & 3;
                const _Float16* src = Wh16t + (size_t)(n0 + row) * DIM + k0 + kk * 32 + ch * 8;
                __builtin_amdgcn_global_load_lds(
                    (const __attribute__((address_space(1))) void*)src,
                    (__attribute__((address_space(3))) void*)&Bbuf[buf][(p * 256 + wbase) * 8],
                    16, 0, 0);
            }
        };

        stage(0, 0);
        stage(1, 64);          // 12 loads in flight

        auto step = [&](auto Sc) {
            constexpr int S   = decltype(Sc)::v;
            constexpr int buf = S & 1;
            if constexpr (S < 7) asm volatile("s_waitcnt vmcnt(6)" ::: "memory");
            else                 asm volatile("s_waitcnt vmcnt(0)" ::: "memory");
            __builtin_amdgcn_sched_barrier(0);
            __builtin_amdgcn_s_barrier();          // all waves' stage(S) landed
            __builtin_amdgcn_sched_barrier(0);

            half8 aF[2][4], bF[2][2];
            #pragma unroll
            for (int kk = 0; kk < 2; ++kk) {
                #pragma unroll
                for (int i = 0; i < 4; ++i)
                    aF[kk][i] = *(const half8*)&Abuf[buf][kk * 2048 + (16 * i + lm) * 32 + lq * 8];
                #pragma unroll
                for (int j = 0; j < 2; ++j)
                    bF[kk][j] = *(const half8*)&Bbuf[buf][kk * 4096 + (wn + 16 * j + lm) * 32 + lq * 8];
            }
            asm volatile("s_waitcnt lgkmcnt(0)" ::: "memory");
            __builtin_amdgcn_sched_barrier(0);
            __builtin_amdgcn_s_barrier();          // WAR: all waves read buf
            __builtin_amdgcn_sched_barrier(0);

            if constexpr (S < 6) stage(buf, (S + 2) * 64);

            #pragma unroll
            for (int kk = 0; kk < 2; ++kk)
                #pragma unroll
                for (int i = 0; i < 4; ++i)
                    #pragma unroll
                    for (int j = 0; j < 2; ++j)
                        acc[i][j] = __builtin_amdgcn_mfma_f32_16x16x32_f16(
                            aF[kk][i], bF[kk][j], acc[i][j], 0, 0, 0);
        };

        step(IC<0>{}); step(IC<1>{}); step(IC<2>{}); step(IC<3>{});
        step(IC<4>{}); step(IC<5>{}); step(IC<6>{}); step(IC<7>{});

        if (mg >= BKT) return;                 // padded m-groups: no edges

        __syncthreads();                       // staging dead; safe to overwrite
        #pragma unroll
        for (int i = 0; i < 4; ++i)
            #pragma unroll
            for (int j = 0; j < 2; ++j)
                #pragma unroll
                for (int r = 0; r < 4; ++r)
                    ZWl[(16 * i + lq * 4 + r) * ZWL_LD + wn + 16 * j + lm] = acc[i][j][r];
        __syncthreads();

        if (t == 0) waitflag_acq(&flags[2], SCAT_N);   // one L1/L2 inv per block
        __syncthreads();

        const int end   = aload(cursor + mg);             // post-scatter = end
        const int start = mg ? aload(cursor + mg - 1) : 0;
        const int gq = l >> 4;      // 4 edges/wave, 16 lanes each
        const int sl = l & 15;

        for (int base = start; base < end; base += 16) {
            const int idx = base + w * 4 + gq;
            float s = 0.f;
            int e = -1;
            if (idx < end) {
                const ull v = slots[idx];
                e = (int)(v & 0x3FFFFu);
                const int c  = (int)((v >> 18) & 0x3FFFu);
                const int rl = (int)(v >> 32) - m0;
                const float* zw = ZWl + rl * ZWL_LD + sl * 8;
                const half8 cv = *(const half8*)(Zh16 + (size_t)c * DIM + n0 + sl * 8);
                const float4 z0 = *(const float4*)(zw);
                const float4 z1 = *(const float4*)(zw + 4);
                s = fmaf(z0.x, (float)cv[0], s);
                s = fmaf(z0.y, (float)cv[1], s);
                s = fmaf(z0.z, (float)cv[2], s);
                s = fmaf(z0.w, (float)cv[3], s);
                s = fmaf(z1.x, (float)cv[4], s);
                s = fmaf(z1.y, (float)cv[5], s);
                s = fmaf(z1.z, (float)cv[6], s);
                s = fmaf(z1.w, (float)cv[7], s);
            }
            s += __shfl_xor(s, 1, 64);
            s += __shfl_xor(s, 2, 64);
            s += __shfl_xor(s, 4, 64);
            s += __shfl_xor(s, 8, 64);
            if (sl == 0 && e >= 0 && e < NEDGES)
                atomicAdd(score_acc + e, s);
        }
        return;
    }

    // ---------------- role: hist by r>>6 (LDS-aggregated) ----------------
    if (bid < SCAN_BID) {
        const int hb = bid - HIST_BASE;        // 0..63
        for (int i = t; i < BKT; i += 256) s_cnt[i] = 0;
        __syncthreads();
        for (int e = hb * 256 + t; e < NEDGES; e += HIST_BLK * 256)
            atomicAdd(&s_cnt[eidx[e] >> 6], 1);
        __syncthreads();
        for (int i = t; i < BKT; i += 256)
            if (s_cnt[i]) atomicAdd(&counts[i], s_cnt[i]);
        __syncthreads();
        if (t == 0) signal(&flags[0]);
        return;
    }

    // ---------------- role: scan (1 block, 157 buckets) ----------------
    if (bid == SCAN_BID) {
        if (t == 0) waitflag(&flags[0], HIST_BLK);
        __syncthreads();
        int v = (t < BKT) ? aload(counts + t) : 0;
        s_scan[t] = v;
        __syncthreads();
        #pragma unroll
        for (int off = 1; off < 256; off <<= 1) {
            int u = (t >= off) ? s_scan[t - off] : 0;
            __syncthreads();
            s_scan[t] += u;
            __syncthreads();
        }
        if (t < BKT) astore(cursor + t, s_scan[t] - v);   // exclusive prefix
        __syncthreads();
        if (t == 0) signal(&flags[1]);
        return;
    }

    // ---------------- role: scatter by r>>6 (LDS range reservation) -------
    {
        const int sb = bid - SCAT_BASE;        // 0..198, 1024 edges each
        for (int i = t; i < BKT; i += 256) { s_cnt[i] = 0; s_off[i] = 0; }
        __syncthreads();
        const int e0 = sb * 1024;
        int myb[4];
        #pragma unroll
        for (int q = 0; q < 4; ++q) {
            int e = e0 + q * 256 + t;
            if (e < NEDGES) { myb[q] = eidx[e] >> 6; atomicAdd(&s_cnt[myb[q]], 1); }
            else myb[q] = -1;
        }
        __syncthreads();
        if (t == 0) waitflag(&flags[1], 1);
        __syncthreads();
        for (int i = t; i < BKT; i += 256)
            if (s_cnt[i]) s_base[i] = atomicAdd(&cursor[i], s_cnt[i]);
        __syncthreads();
        #pragma unroll
        for (int q = 0; q < 4; ++q)
            if (myb[q] >= 0) {
                int e = e0 + q * 256 + t;
                int r = eidx[e];
                int c = eidx[NEDGES + e];
                int pos = s_base[myb[q]] + atomicAdd(&s_off[myb[q]], 1);
                slots[pos] = ((ull)(unsigned)r << 32) |
                             (ull)(((unsigned)c << 18) | (unsigned)e);
            }
        __syncthreads();                       // vmcnt(0): stores accepted by L2
        if (t == 0) signal_rel(&flags[2]);     // RELEASE: write back XCD L2
    }
}

// ---------------------------------------------------------------------------
// Final: sigmoid over accumulated partials (contiguous, trivially BW-bound).
// ---------------------------------------------------------------------------
__global__ __launch_bounds__(256) void sigmoid_out(const float* __restrict__ acc,
                                                   float* __restrict__ out) {
    const int i = blockIdx.x * 256 + threadIdx.x;
    if (i < NEDGES / 4) {
        float4 v = ((const float4*)acc)[i];
        float4 o;
        o.x = 1.0f / (1.0f + expf(-v.x));
        o.y = 1.0f / (1.0f + expf(-v.y));
        o.z = 1.0f / (1.0f + expf(-v.z));
        o.w = 1.0f / (1.0f + expf(-v.w));
        ((float4*)out)[i] = o;
    }
}

// ---------------------------------------------------------------------------
// fp32 fallback path (ws too small)
// ---------------------------------------------------------------------------
#define GTM 128
#define GTN 64
#define GTK 16
#define LDA 132
#define LDB 68

__global__ __launch_bounds__(256) void gemm_zw(const float* __restrict__ A,
                                               const float* __restrict__ B,
                                               float* __restrict__ C) {
    __shared__ float As[GTK * LDA];
    __shared__ float Bs[GTK * LDB];

    const int t  = threadIdx.x;
    const int m0 = blockIdx.x * GTM;
    const int n0 = blockIdx.y * GTN;
    const int tx = t & 15;
    const int ty = t >> 4;

    float acc[8][4] = {};

    for (int k0 = 0; k0 < DIM; k0 += GTK) {
        #pragma unroll
        for (int p = 0; p < 2; ++p) {
            int f  = t + p * 256;
            int mm = f >> 2;
            int kq = f & 3;
            int m  = m0 + mm;
            float4 v = make_float4(0.f, 0.f, 0.f, 0.f);
            if (m < NNODES)
                v = *(const float4*)(A + (size_t)m * DIM + k0 + kq * 4);
            As[(kq * 4 + 0) * LDA + mm] = v.x;
            As[(kq * 4 + 1) * LDA + mm] = v.y;
            As[(kq * 4 + 2) * LDA + mm] = v.z;
            As[(kq * 4 + 3) * LDA + mm] = v.w;
        }
        {
            int kb = t >> 4, n4 = t & 15;
            *(float4*)&Bs[kb * LDB + n4 * 4] =
                *(const float4*)(B + (size_t)(k0 + kb) * DIM + n0 + n4 * 4);
        }
        __syncthreads();

        #pragma unroll
        for (int kk = 0; kk < GTK; ++kk) {
            float4 a0 = *(const float4*)&As[kk * LDA + ty * 8];
            float4 a1 = *(const float4*)&As[kk * LDA + ty * 8 + 4];
            float4 b  = *(const float4*)&Bs[kk * LDB + tx * 4];
            float av[8] = {a0.x, a0.y, a0.z, a0.w, a1.x, a1.y, a1.z, a1.w};
            float bv[4] = {b.x, b.y, b.z, b.w};
            #pragma unroll
            for (int i = 0; i < 8; ++i)
                #pragma unroll
                for (int j = 0; j < 4; ++j)
                    acc[i][j] = fmaf(av[i], bv[j], acc[i][j]);
        }
        __syncthreads();
    }

    #pragma unroll
    for (int i = 0; i < 8; ++i) {
        int m = m0 + ty * 8 + i;
        if (m < NNODES)
            *(float4*)(C + (size_t)m * DIM + n0 + tx * 4) =
                make_float4(acc[i][0], acc[i][1], acc[i][2], acc[i][3]);
    }
}

__global__ __launch_bounds__(256) void edge_score(const float* __restrict__ ZW,
                                                  const float* __restrict__ Z,
                                                  const int* __restrict__ eidx,
                                                  float* __restrict__ out) {
    const int e    = blockIdx.x * 4 + (threadIdx.x >> 6);
    const int lane = threadIdx.x & 63;

    const int r = eidx[e];
    const int c = eidx[NEDGES + e];

    const float4* pr = (const float4*)(ZW + (size_t)r * DIM);
    const float4* pc = (const float4*)(Z  + (size_t)c * DIM);

    float4 a0 = pr[lane * 2 + 0];
    float4 a1 = pr[lane * 2 + 1];
    float4 b0 = pc[lane * 2 + 0];
    float4 b1 = pc[lane * 2 + 1];

    float s = a0.x * b0.x;
    s = fmaf(a0.y, b0.y, s);
    s = fmaf(a0.z, b0.z, s);
    s = fmaf(a0.w, b0.w, s);
    s = fmaf(a1.x, b1.x, s);
    s = fmaf(a1.y, b1.y, s);
    s = fmaf(a1.z, b1.z, s);
    s = fmaf(a1.w, b1.w, s);

    #pragma unroll
    for (int off = 32; off > 0; off >>= 1)
        s += __shfl_xor(s, off, 64);

    if (lane == 0)
        out[e] = 1.0f / (1.0f + expf(-s));
}

// ---------------------------------------------------------------------------
extern "C" void kernel_launch(void* const* d_in, const int* in_sizes, int n_in,
                              void* d_out, int out_size, void* d_ws, size_t ws_size,
                              hipStream_t stream) {
    const float* Z  = (const float*)d_in[0];
    const float* W  = (const float*)d_in[1];
    const int*   EI = (const int*)d_in[2];
    float* out = (float*)d_out;

    char* p = (char*)d_ws;
    _Float16* Zh16  = (_Float16*)p;  p += (size_t)MPAD * DIM * 2;
    _Float16* Wh16t = (_Float16*)p;  p += (size_t)DIM * DIM * 2;
    int* counts  = (int*)p;          p += (size_t)BKT * 4;
    int* flags   = (int*)p;          p += 4 * 4;     // adjacent to counts
    int* cursor  = (int*)p;          p += (size_t)BKT * 4;
    ull* slots   = (ull*)p;          p += (size_t)NEDGES * 8;
    float* score_acc = (float*)p;    p += (size_t)NEDGES * 4;
    const size_t need_full = (size_t)(p - (char*)d_ws);

    if (ws_size >= need_full) {
        prep<<<PREP_GRID, 256, 0, stream>>>(Z, W, Zh16, Wh16t, counts, score_acc);
        gemm_sort<<<FUSE_GRID, 256, 0, stream>>>(Zh16, Wh16t, EI, counts,
                                                 cursor, slots, score_acc, flags);
        sigmoid_out<<<(NEDGES / 4 + 255) / 256, 256, 0, stream>>>(score_acc, out);
    } else {
        float* ZW = (float*)d_ws;
        dim3 g1((NNODES + GTM - 1) / GTM, DIM / GTN);
        gemm_zw<<<g1, 256, 0, stream>>>(Z, W, ZW);
        edge_score<<<NEDGES / 4, 256, 0, stream>>>(ZW, Z, EI, out);
    }
}

// Round 13
// 138.067 us; speedup vs baseline: 1.5823x; 1.5823x over previous
//
#include <hip/hip_runtime.h>
#include <math.h>

#define DIM     512
#define NNODES  10000
#define NEDGES  200000
#define MPAD    10240   // 160 * 64 (padded so XCD packing is exact)
#define NMB     160     // m-groups of 64
#define GEMM_GRID (NMB * 4)       // 640 pure-GEMM blocks

using floatx4 = __attribute__((ext_vector_type(4))) float;
using half8   = __attribute__((ext_vector_type(8))) _Float16;
using half2v  = __attribute__((ext_vector_type(2))) _Float16;

template <int N> struct IC { static constexpr int v = N; };

__device__ inline float dot2acc(half2v a, half2v b, float c) {
#if __has_builtin(__builtin_amdgcn_fdot2)
    return __builtin_amdgcn_fdot2(a, b, c, false);
#else
    return fmaf((float)a[0], (float)b[0], fmaf((float)a[1], (float)b[1], c));
#endif
}

// ---------------------------------------------------------------------------
// prep: (a) Z fp32 -> Zh16 fp16 [MPAD][512] (pad rows zeroed)
//       (b) W fp32 [k][n] -> Wh16t fp16 [n][k] (LDS tile transpose)
// R13 = R9 (best measured, 128.7us) with ONLY the scorer changed.
// Sort-based locality is abandoned: R10 net -3.5us, R11 cross-XCD race,
// R12 residency inversion (GEMM blocks spinning on scatter blocks that
// couldn't launch) -> 155us. GEMM blocks must never wait (R3 rule).
// ---------------------------------------------------------------------------
#define PREP_ZBLK 2560            // MPAD*512/(256*8)
#define PREP_GRID (PREP_ZBLK + 64)
__global__ __launch_bounds__(256) void prep(const float* __restrict__ Z,
                                            const float* __restrict__ W,
                                            _Float16* __restrict__ Zh16,
                                            _Float16* __restrict__ Wh16t) {
    const int b = blockIdx.x;
    const int t = threadIdx.x;

    if (b < PREP_ZBLK) {
        const int idx8 = (b * 256 + t) * 8;
        const int m = idx8 >> 9;
        float x[8];
        if (m < NNODES) {
            float4 v0 = *(const float4*)(Z + idx8);
            float4 v1 = *(const float4*)(Z + idx8 + 4);
            x[0]=v0.x; x[1]=v0.y; x[2]=v0.z; x[3]=v0.w;
            x[4]=v1.x; x[5]=v1.y; x[6]=v1.z; x[7]=v1.w;
        } else {
            #pragma unroll
            for (int j = 0; j < 8; ++j) x[j] = 0.f;
        }
        half8 h;
        #pragma unroll
        for (int j = 0; j < 8; ++j) h[j] = (_Float16)x[j];
        *(half8*)(Zh16 + idx8) = h;
    } else {
        __shared__ float tile[64][65];
        const int wb = b - PREP_ZBLK;      // 0..63
        const int kb = (wb >> 3) * 64;
        const int nb = (wb & 7) * 64;
        const int kk = t >> 2;
        const int ch = t & 3;

        const float* src = W + (size_t)(kb + kk) * DIM + nb + ch * 16;
        #pragma unroll
        for (int q = 0; q < 4; ++q) {
            float4 v = *(const float4*)(src + q * 4);
            tile[kk][ch * 16 + q * 4 + 0] = v.x;
            tile[kk][ch * 16 + q * 4 + 1] = v.y;
            tile[kk][ch * 16 + q * 4 + 2] = v.z;
            tile[kk][ch * 16 + q * 4 + 3] = v.w;
        }
        __syncthreads();

        const int nn = kk;
        half8 h0, h1;
        #pragma unroll
        for (int i = 0; i < 8; ++i) h0[i] = (_Float16)tile[ch * 16 + i][nn];
        #pragma unroll
        for (int i = 0; i < 8; ++i) h1[i] = (_Float16)tile[ch * 16 + 8 + i][nn];
        _Float16* d = Wh16t + (size_t)(nb + nn) * DIM + kb + ch * 16;
        *(half8*)(d)     = h0;
        *(half8*)(d + 8) = h1;
    }
}

// ---------------------------------------------------------------------------
// Pure GEMM: 64x128 tiles, counted-vmcnt 2-deep pipeline (R7) + XCD packing
// (R6). Grid 640 @ 3 blocks/CU -> all blocks resident, single generation.
// (R9-verbatim; measured ~25us standalone.)
// ---------------------------------------------------------------------------
__global__ __launch_bounds__(256, 3) void gemm_f16(
        const _Float16* __restrict__ Zh16,
        const _Float16* __restrict__ Wh16t,
        _Float16* __restrict__ ZWh)
{
    __shared__ _Float16 Abuf[2][2 * 64 * 32];    // 16 KB
    __shared__ _Float16 Bbuf[2][2 * 128 * 32];   // 32 KB

    const int t   = threadIdx.x;
    const int bid = blockIdx.x;

    const int cxd = bid & 7;              // XCD class (bid%8 -> XCD)
    const int rr  = bid >> 3;             // 0..79
    const int mg  = (rr >> 2) * 8 + cxd;  // 0..159, same-m => same XCD
    const int m0  = mg * 64;
    const int n0  = (rr & 3) * 128;

    const int l  = t & 63;
    const int w  = t >> 6;
    const int wn = w * 32;
    const int lm = l & 15;
    const int lq = l >> 4;
    const unsigned wbase = (unsigned)(t & 192);

    floatx4 acc[4][2] = {};

    auto stage = [&](int buf, int k0) {    // 6 global_load_lds / thread
        #pragma unroll
        for (int p = 0; p < 2; ++p) {
            const int s   = p * 256 + t;
            const int kk  = s >> 8;
            const int row = (s >> 2) & 63;
            const int ch  = s & 3;
            const _Float16* src = Zh16 + (size_t)(m0 + row) * DIM + k0 + kk * 32 + ch * 8;
            __builtin_amdgcn_global_load_lds(
                (const __attribute__((address_space(1))) void*)src,
                (__attribute__((address_space(3))) void*)&Abuf[buf][(p * 256 + wbase) * 8],
                16, 0, 0);
        }
        #pragma unroll
        for (int p = 0; p < 4; ++p) {
            const int s   = p * 256 + t;
            const int kk  = s >> 9;
            const int row = (s >> 2) & 127;
            const int ch  = s & 3;
            const _Float16* src = Wh16t + (size_t)(n0 + row) * DIM + k0 + kk * 32 + ch * 8;
            __builtin_amdgcn_global_load_lds(
                (const __attribute__((address_space(1))) void*)src,
                (__attribute__((address_space(3))) void*)&Bbuf[buf][(p * 256 + wbase) * 8],
                16, 0, 0);
        }
    };

    stage(0, 0);
    stage(1, 64);          // 12 loads in flight

    auto step = [&](auto Sc) {
        constexpr int S   = decltype(Sc)::v;
        constexpr int buf = S & 1;
        // stage(S) complete; stage(S+1)'s 6 loads stay in flight
        if constexpr (S < 7) asm volatile("s_waitcnt vmcnt(6)" ::: "memory");
        else                 asm volatile("s_waitcnt vmcnt(0)" ::: "memory");
        __builtin_amdgcn_sched_barrier(0);
        __builtin_amdgcn_s_barrier();          // all waves' stage(S) landed
        __builtin_amdgcn_sched_barrier(0);

        half8 aF[2][4], bF[2][2];
        #pragma unroll
        for (int kk = 0; kk < 2; ++kk) {
            #pragma unroll
            for (int i = 0; i < 4; ++i)
                aF[kk][i] = *(const half8*)&Abuf[buf][kk * 2048 + (16 * i + lm) * 32 + lq * 8];
            #pragma unroll
            for (int j = 0; j < 2; ++j)
                bF[kk][j] = *(const half8*)&Bbuf[buf][kk * 4096 + (wn + 16 * j + lm) * 32 + lq * 8];
        }
        asm volatile("s_waitcnt lgkmcnt(0)" ::: "memory");
        __builtin_amdgcn_sched_barrier(0);
        __builtin_amdgcn_s_barrier();          // WAR: all waves read buf
        __builtin_amdgcn_sched_barrier(0);

        if constexpr (S < 6) stage(buf, (S + 2) * 64);   // refill freed buf

        #pragma unroll
        for (int kk = 0; kk < 2; ++kk)
            #pragma unroll
            for (int i = 0; i < 4; ++i)
                #pragma unroll
                for (int j = 0; j < 2; ++j)
                    acc[i][j] = __builtin_amdgcn_mfma_f32_16x16x32_f16(
                        aF[kk][i], bF[kk][j], acc[i][j], 0, 0, 0);
    };

    step(IC<0>{}); step(IC<1>{}); step(IC<2>{}); step(IC<3>{});
    step(IC<4>{}); step(IC<5>{}); step(IC<6>{}); step(IC<7>{});

    #pragma unroll
    for (int i = 0; i < 4; ++i)
        #pragma unroll
        for (int j = 0; j < 2; ++j)
            #pragma unroll
            for (int r = 0; r < 4; ++r) {
                const int gm = m0 + 16 * i + lq * 4 + r;
                const int gn = n0 + wn + 16 * j + lm;
                if (gm < NNODES)
                    ZWh[(size_t)gm * DIM + gn] = (_Float16)acc[i][j][r];
            }
}

// ---------------------------------------------------------------------------
// Edge scoring, unsorted, MLP-doubled: each 16-lane group handles TWO edges;
// per lane 16 independent b128 loads in flight (was 8), and each edge's dot
// uses 2 independent accumulators (was 1 serial chain). R9's scorer showed
// 47.6us @ 63% occupancy, VALUBusy 13% -- latency-limited signature.
// ---------------------------------------------------------------------------
__global__ __launch_bounds__(256) void edge_score_u(const _Float16* __restrict__ ZWh,
                                                    const _Float16* __restrict__ Zh,
                                                    const int* __restrict__ eidx,
                                                    float* __restrict__ out) {
    const int t    = threadIdx.x;
    const int lane = t & 63;
    const int gq   = lane >> 4;
    const int sl   = lane & 15;

    const int e0 = blockIdx.x * 32 + (t >> 6) * 8 + gq * 2;   // 2 edges/group
    const int e1 = e0 + 1;

    const int r0 = eidx[e0], c0 = eidx[NEDGES + e0];
    const int r1 = eidx[e1], c1 = eidx[NEDGES + e1];

    const _Float16* rp0 = ZWh + (size_t)r0 * DIM + sl * 32;
    const _Float16* cp0 = Zh  + (size_t)c0 * DIM + sl * 32;
    const _Float16* rp1 = ZWh + (size_t)r1 * DIM + sl * 32;
    const _Float16* cp1 = Zh  + (size_t)c1 * DIM + sl * 32;

    half8 a0[4], b0[4], a1[4], b1[4];
    #pragma unroll
    for (int q = 0; q < 4; ++q) {
        a0[q] = *(const half8*)(rp0 + q * 8);
        b0[q] = *(const half8*)(cp0 + q * 8);
        a1[q] = *(const half8*)(rp1 + q * 8);
        b1[q] = *(const half8*)(cp1 + q * 8);
    }

    float s0a = 0.f, s0b = 0.f, s1a = 0.f, s1b = 0.f;
    #pragma unroll
    for (int q = 0; q < 4; ++q) {
        #pragma unroll
        for (int d = 0; d < 2; ++d) {
            s0a = dot2acc((half2v){a0[q][2*d],     a0[q][2*d + 1]},
                          (half2v){b0[q][2*d],     b0[q][2*d + 1]}, s0a);
            s0b = dot2acc((half2v){a0[q][2*d + 4], a0[q][2*d + 5]},
                          (half2v){b0[q][2*d + 4], b0[q][2*d + 5]}, s0b);
            s1a = dot2acc((half2v){a1[q][2*d],     a1[q][2*d + 1]},
                          (half2v){b1[q][2*d],     b1[q][2*d + 1]}, s1a);
            s1b = dot2acc((half2v){a1[q][2*d + 4], a1[q][2*d + 5]},
                          (half2v){b1[q][2*d + 4], b1[q][2*d + 5]}, s1b);
        }
    }

    float s0 = s0a + s0b;
    float s1 = s1a + s1b;

    s0 += __shfl_xor(s0, 1, 64);
    s0 += __shfl_xor(s0, 2, 64);
    s0 += __shfl_xor(s0, 4, 64);
    s0 += __shfl_xor(s0, 8, 64);
    s1 += __shfl_xor(s1, 1, 64);
    s1 += __shfl_xor(s1, 2, 64);
    s1 += __shfl_xor(s1, 4, 64);
    s1 += __shfl_xor(s1, 8, 64);

    if (sl == 0) {
        out[e0] = 1.0f / (1.0f + expf(-s0));
        out[e1] = 1.0f / (1.0f + expf(-s1));
    }
}

// ---------------------------------------------------------------------------
// fp32 fallback path (ws too small)
// ---------------------------------------------------------------------------
#define GTM 128
#define GTN 64
#define GTK 16
#define LDA 132
#define LDB 68

__global__ __launch_bounds__(256) void gemm_zw(const float* __restrict__ A,
                                               const float* __restrict__ B,
                                               float* __restrict__ C) {
    __shared__ float As[GTK * LDA];
    __shared__ float Bs[GTK * LDB];

    const int t  = threadIdx.x;
    const int m0 = blockIdx.x * GTM;
    const int n0 = blockIdx.y * GTN;
    const int tx = t & 15;
    const int ty = t >> 4;

    float acc[8][4] = {};

    for (int k0 = 0; k0 < DIM; k0 += GTK) {
        #pragma unroll
        for (int p = 0; p < 2; ++p) {
            int f  = t + p * 256;
            int mm = f >> 2;
            int kq = f & 3;
            int m  = m0 + mm;
            float4 v = make_float4(0.f, 0.f, 0.f, 0.f);
            if (m < NNODES)
                v = *(const float4*)(A + (size_t)m * DIM + k0 + kq * 4);
            As[(kq * 4 + 0) * LDA + mm] = v.x;
            As[(kq * 4 + 1) * LDA + mm] = v.y;
            As[(kq * 4 + 2) * LDA + mm] = v.z;
            As[(kq * 4 + 3) * LDA + mm] = v.w;
        }
        {
            int kb = t >> 4, n4 = t & 15;
            *(float4*)&Bs[kb * LDB + n4 * 4] =
                *(const float4*)(B + (size_t)(k0 + kb) * DIM + n0 + n4 * 4);
        }
        __syncthreads();

        #pragma unroll
        for (int kk = 0; kk < GTK; ++kk) {
            float4 a0 = *(const float4*)&As[kk * LDA + ty * 8];
            float4 a1 = *(const float4*)&As[kk * LDA + ty * 8 + 4];
            float4 b  = *(const float4*)&Bs[kk * LDB + tx * 4];
            float av[8] = {a0.x, a0.y, a0.z, a0.w, a1.x, a1.y, a1.z, a1.w};
            float bv[4] = {b.x, b.y, b.z, b.w};
            #pragma unroll
            for (int i = 0; i < 8; ++i)
                #pragma unroll
                for (int j = 0; j < 4; ++j)
                    acc[i][j] = fmaf(av[i], bv[j], acc[i][j]);
        }
        __syncthreads();
    }

    #pragma unroll
    for (int i = 0; i < 8; ++i) {
        int m = m0 + ty * 8 + i;
        if (m < NNODES)
            *(float4*)(C + (size_t)m * DIM + n0 + tx * 4) =
                make_float4(acc[i][0], acc[i][1], acc[i][2], acc[i][3]);
    }
}

__global__ __launch_bounds__(256) void edge_score(const float* __restrict__ ZW,
                                                  const float* __restrict__ Z,
                                                  const int* __restrict__ eidx,
                                                  float* __restrict__ out) {
    const int e    = blockIdx.x * 4 + (threadIdx.x >> 6);
    const int lane = threadIdx.x & 63;

    const int r = eidx[e];
    const int c = eidx[NEDGES + e];

    const float4* pr = (const float4*)(ZW + (size_t)r * DIM);
    const float4* pc = (const float4*)(Z  + (size_t)c * DIM);

    float4 a0 = pr[lane * 2 + 0];
    float4 a1 = pr[lane * 2 + 1];
    float4 b0 = pc[lane * 2 + 0];
    float4 b1 = pc[lane * 2 + 1];

    float s = a0.x * b0.x;
    s = fmaf(a0.y, b0.y, s);
    s = fmaf(a0.z, b0.z, s);
    s = fmaf(a0.w, b0.w, s);
    s = fmaf(a1.x, b1.x, s);
    s = fmaf(a1.y, b1.y, s);
    s = fmaf(a1.z, b1.z, s);
    s = fmaf(a1.w, b1.w, s);

    #pragma unroll
    for (int off = 32; off > 0; off >>= 1)
        s += __shfl_xor(s, off, 64);

    if (lane == 0)
        out[e] = 1.0f / (1.0f + expf(-s));
}

// ---------------------------------------------------------------------------
extern "C" void kernel_launch(void* const* d_in, const int* in_sizes, int n_in,
                              void* d_out, int out_size, void* d_ws, size_t ws_size,
                              hipStream_t stream) {
    const float* Z  = (const float*)d_in[0];
    const float* W  = (const float*)d_in[1];
    const int*   EI = (const int*)d_in[2];
    float* out = (float*)d_out;

    char* p = (char*)d_ws;
    _Float16* ZWh   = (_Float16*)p;  p += (size_t)MPAD * DIM * 2;
    _Float16* Zh16  = (_Float16*)p;  p += (size_t)MPAD * DIM * 2;
    _Float16* Wh16t = (_Float16*)p;  p += (size_t)DIM * DIM * 2;
    const size_t need_full = (size_t)(p - (char*)d_ws);

    if (ws_size >= need_full) {
        prep<<<PREP_GRID, 256, 0, stream>>>(Z, W, Zh16, Wh16t);
        gemm_f16<<<GEMM_GRID, 256, 0, stream>>>(Zh16, Wh16t, ZWh);
        edge_score_u<<<NEDGES / 32, 256, 0, stream>>>(ZWh, Zh16, EI, out);
    } else {
        float* ZW = (float*)d_ws;
        dim3 g1((NNODES + GTM - 1) / GTM, DIM / GTN);
        gemm_zw<<<g1, 256, 0, stream>>>(Z, W, ZW);
        edge_score<<<NEDGES / 4, 256, 0, stream>>>(ZW, Z, EI, out);
    }
}